// Round 4
// baseline (95.445 us; speedup 1.0000x reference)
//
#include <hip/hip_runtime.h>
#include <stdint.h>

// out[b,j,:] = sym[b,j,:] + sum_{i!=j} (sym[b,i,:] @ W[rel(i,j)].T + bias[rel(i,j)])
// B=8, N=1024, D=128, 6 relations.
//
// Linearity rewrite:  agg[j] = sum_r (sum_{i!=j, rel=r} sym[i]) @ W[r].T + cnt_r(j)*bias[r]
//
// R14 (this round):
//  - R13's cooperative launch crashed the harness (graph capture of
//    hipLaunchCooperativeKernel unsupported) -> back to 2 dispatches.
//  - Main bet: all 40-45us variants used LDS=81920, 2x81920 == exactly the
//    160KiB pool. Any runtime LDS reserve silently drops to 1 block/CU
//    (2 waves/SIMD, grid runs in 2 occupancy rounds) — the only hypothesis
//    that quantitatively explains the stuck ~40us vs ~13us issue model.
//    Fix: LDS -> 49536 B (2 blocks/CU guaranteed, 3 possible if VGPR<=84):
//      * B staging: 64-i chunks, 2x16KB double buffer (R12's proven DMA
//        geometry), barrier-free, counted vmcnt(2).
//      * phase 3 rewritten: each wave owns a 16-e output slice, full K=768
//        (24 MFMA) -> kills the 33.8KB fp32 partial buffer, the K-split
//        reduce and 2 barriers. Counts -> 384B LDS, computed post-classify.
//  - Phase 2 keeps R11's in-wave mul24 mask expansion (cheapest measured
//    form), 5 relations + S5 complement from precomputed T4 colsums.

typedef __attribute__((ext_vector_type(8))) short bf16x8;
typedef __attribute__((ext_vector_type(4))) float f32x4;
union U4B { uint4 u; bf16x8 b; };

#if defined(__has_builtin)
#  if __has_builtin(__builtin_amdgcn_global_load_lds)
#    define HAVE_GLL 1
#  endif
#  if __has_builtin(__builtin_amdgcn_mul_u24)
#    define OH_MUL24 1
#  endif
#endif

__device__ __forceinline__ uint16_t f2bf(float f) {
    union { float f; uint32_t u; } v; v.f = f;
    uint32_t u = v.u;
    uint32_t r = (u + 0x7FFFu + ((u >> 16) & 1u)) >> 16;  // RNE
    return (uint16_t)r;
}

// raw barrier: orders LDS only; never drains vmcnt (DMA stays in flight).
#define BARRIER_LGKM() do {                                   \
    asm volatile("s_waitcnt lgkmcnt(0)" ::: "memory");        \
    __builtin_amdgcn_s_barrier();                             \
    asm volatile("" ::: "memory");                            \
} while (0)

// ---------------------------------------------------------------------------
// prep: blocks 0..255: transpose X[b][i][e] fp32 -> symT[b][e][i] bf16 (64x64)
//       blocks 256..351: W[r][ep][e] fp32 -> WtB blocked bf16
//       blocks 352..383: T4[b][qq][e] = sum_{i in qq*256..+256} X[b][i][e]
// ---------------------------------------------------------------------------
__global__ __launch_bounds__(256)
void prep_kernel(const float* __restrict__ X, const float* __restrict__ W,
                 uint16_t* __restrict__ symT, uint16_t* __restrict__ WtB,
                 float* __restrict__ T4) {
    const int blk = blockIdx.x, tid = threadIdx.x;
    if (blk < 256) {
        __shared__ float T[64 * 65];
        const int b = blk & 7, z = blk >> 3, it = z & 15, et = z >> 4;
        const int i0 = it * 64, e0 = et * 64;
        const float4* Xf = (const float4*)X;
#pragma unroll
        for (int s = 0; s < 4; ++s) {
            int il = s * 16 + (tid >> 4), e4 = tid & 15;
            float4 v = Xf[((size_t)b << 15) + (size_t)((i0 + il) << 5) + (e0 >> 2) + e4];
            T[il * 65 + e4 * 4 + 0] = v.x;
            T[il * 65 + e4 * 4 + 1] = v.y;
            T[il * 65 + e4 * 4 + 2] = v.z;
            T[il * 65 + e4 * 4 + 3] = v.w;
        }
        __syncthreads();
#pragma unroll
        for (int s = 0; s < 4; ++s) {
            int el = s * 16 + (tid >> 4), il4 = tid & 15;
            uint16_t h0 = f2bf(T[(il4 * 4 + 0) * 65 + el]);
            uint16_t h1 = f2bf(T[(il4 * 4 + 1) * 65 + el]);
            uint16_t h2 = f2bf(T[(il4 * 4 + 2) * 65 + el]);
            uint16_t h3 = f2bf(T[(il4 * 4 + 3) * 65 + el]);
            uint2 pk = { (uint32_t)h0 | ((uint32_t)h1 << 16),
                         (uint32_t)h2 | ((uint32_t)h3 << 16) };
            *(uint2*)&symT[((size_t)b << 17) + ((size_t)(e0 + el) << 10) + i0 + il4 * 4] = pk;
        }
    } else if (blk < 352) {
        int g = (blk - 256) * 256 + tid;          // 0..24575 float4s of W
        float4 v = ((const float4*)W)[g];
        int r = g >> 12, rem = g & 4095, ep = rem >> 5, e4 = rem & 31;
        int kb = r * 4 + (e4 >> 3);               // k = r*128 + e4*4+t
        int kc = (e4 & 7) * 4;
        uint16_t h0 = f2bf(v.x), h1 = f2bf(v.y), h2 = f2bf(v.z), h3 = f2bf(v.w);
        uint2 pk = { (uint32_t)h0 | ((uint32_t)h1 << 16),
                     (uint32_t)h2 | ((uint32_t)h3 << 16) };
        *(uint2*)&WtB[((size_t)(kb * 128 + ep)) * 32 + kc] = pk;
    } else {
        // T4: per-b quarter column sums (fp32), 32 blocks = (b, quarter)
        const int z = blk - 352, bb = z >> 2, qq = z & 3;
        const int e = tid & 127, half = tid >> 7;
        const float* base = X + (((size_t)(bb << 10) + (qq << 8) + (half << 7)) << 7) + e;
        float s = 0.f;
#pragma unroll 8
        for (int itr = 0; itr < 128; ++itr) s += base[(size_t)itr << 7];
        __shared__ float red[256];
        red[tid] = s;
        __syncthreads();
        if (tid < 128) T4[(z << 7) + tid] = red[tid] + red[tid + 128];
    }
}

// ---------------------------------------------------------------------------
// fused kernel: grid 512 = 8b x 64jt (16 j per block), 512 thr = 8 waves.
// LDS map (49536 B -> >=2 blocks/CU guaranteed, 3 if VGPR<=84):
//   @0      B double buffer: 2 x 16384 (64-i chunk; wave w owns [w*2048,+2048):
//           16 e-rows x 128 B, 16B segs XOR-swizzled seg' = seg ^ (e&7)).
//           buf1 head (@16384, 8KB) doubles as posS during classify.
//           After phase 2 the region holds SA: 16 j-rows x 768 k bf16,
//           row stride SP=776 halfwords (24832 B).
//   @32768  rel32: 16 j x 256 dwords, dword-index XOR swizzle (d ^ 2j), 16KB.
//   @49152  cntL: 16 j x 6 relations, float, 384 B.
// ---------------------------------------------------------------------------
#define SP 776

__global__ __launch_bounds__(512, 4)
void fused_kernel(const float* __restrict__ X, const float* __restrict__ pos,
                  const uint16_t* __restrict__ symT, const uint16_t* __restrict__ WtB,
                  const float* __restrict__ bias, const float* __restrict__ T4,
                  float* __restrict__ out) {
    __shared__ __align__(16) char smem[49536];
    float2*   posS  = (float2*)(smem + 16384);
    uint16_t* SA    = (uint16_t*)smem;
    uint32_t* rel32 = (uint32_t*)(smem + 32768);
    float*    cntL  = (float*)(smem + 49152);

    const int blk = blockIdx.x;
    const int b = blk & 7, jt = blk >> 3, j0 = jt * 16;
    const int tid = threadIdx.x;
    const int w = tid >> 6, lane = tid & 63, m = lane & 15, q = lane >> 4;

    const uint16_t* symTb = symT + ((size_t)b << 17);

    // --- B staging: wave w DMAs its own 16 e-rows, 64-i chunks, 2 issues ---
    // issue s, lane l: e = w*16 + s*8 + (l>>3); dest seg t = l&7 holds global
    // seg t ^ (e&7)  (consumer reads seg' = seg ^ (e&7)).
    int goff[2];
#pragma unroll
    for (int s = 0; s < 2; ++s) {
        int e = (w << 4) + (s << 3) + (lane >> 3);
        int t = lane & 7;
        goff[s] = (e << 10) + ((t ^ (e & 7)) << 3);   // halfword units; + c*64
    }

    auto issue_chunk = [&](int cidx, int bufsel) {
#ifdef HAVE_GLL
#pragma unroll
        for (int s = 0; s < 2; ++s) {
            const uint16_t* gp = symTb + goff[s] + cidx * 64;
            char* lp = smem + bufsel * 16384 + (w << 11) + (s << 10);  // wave-uniform
            typedef const __attribute__((address_space(1))) uint32_t gu32;
            typedef __attribute__((address_space(3))) uint32_t lu32;
            __builtin_amdgcn_global_load_lds((gu32*)gp, (lu32*)lp, 16, 0, 0);
        }
#else
#pragma unroll
        for (int s = 0; s < 2; ++s) {
            uint4 v = *(const uint4*)(symTb + goff[s] + cidx * 64);
            *(uint4*)(smem + bufsel * 16384 + (w << 11) + (s << 10) + lane * 16) = v;
        }
#endif
    };

    // ---- phase 0: chunk-0 DMA in flight under classify; stage positions ----
    issue_chunk(0, 0);
    const float2* pos2 = (const float2*)pos + ((size_t)b << 10);
    float2 p0 = pos2[tid], p1 = pos2[tid + 512];
    posS[tid] = p0;
    posS[tid + 512] = p1;
    BARRIER_LGKM();

    // ---- phase 1: classify 16 j x 1024 i -> one-hot bytes (0 on diagonal) ----
    {
        const int mm = tid & 15, grp = tid >> 4;    // grp 0..31: 32 i's each
        const int j = j0 + mm;
        const float2 pj = posS[j];
        uint32_t* dst = &rel32[mm * 256];
        const int sw = mm * 2;                      // dword-index XOR swizzle
#pragma unroll
        for (int s = 0; s < 8; ++s) {
            uint32_t word = 0;
#pragma unroll
            for (int qq = 0; qq < 4; ++qq) {
                int i = grp * 32 + s * 4 + qq;
                float2 pi = posS[i];
                float dx = pj.x - pi.x, dy = pj.y - pi.y;
                // faithful priority chain of _get_relation_type
                int r = (dy > 0.5f) ? 0
                      : (dy < -0.5f) ? 1
                      : (dx < -0.5f) ? 2
                      : (dx > 0.5f)  ? 3
                      : (fabsf(dx) < 0.3f && fabsf(dy) < 0.3f) ? 4
                      : 5;
                uint32_t oh = (i == j) ? 0u : (1u << r);
                word |= oh << (8 * qq);
            }
            dst[(grp * 8 + s) ^ sw] = word;
        }
    }
    BARRIER_LGKM();            // rel32 ready; posS dead

    // ---- counts: cnt_r(j) from rel32 (swizzle is a row-internal permutation,
    //      popcount-invariant); cnt5 = 1023 - sum. Written to cntL; visibility
    //      for the epilogue is covered by the post-phase2 barrier. ----
    {
        const int j = tid >> 5, t = tid & 31;
        const uint32_t* row = &rel32[j * 256 + t * 8];
        uint32_t s0 = 0, s1 = 0, s2 = 0, s3 = 0, s4 = 0;
#pragma unroll
        for (int k = 0; k < 8; ++k) {
            uint32_t wd = row[k];
            s0 += wd & 0x01010101u;        s1 += (wd >> 1) & 0x01010101u;
            s2 += (wd >> 2) & 0x01010101u; s3 += (wd >> 3) & 0x01010101u;
            s4 += (wd >> 4) & 0x01010101u;
        }
        int cnt[6];
        cnt[0] = (int)((s0 * 0x01010101u) >> 24);
        cnt[1] = (int)((s1 * 0x01010101u) >> 24);
        cnt[2] = (int)((s2 * 0x01010101u) >> 24);
        cnt[3] = (int)((s3 * 0x01010101u) >> 24);
        cnt[4] = (int)((s4 * 0x01010101u) >> 24);
#pragma unroll
        for (int off = 1; off < 32; off <<= 1)
#pragma unroll
            for (int r = 0; r < 5; ++r)
                cnt[r] += __shfl_xor(cnt[r], off, 64);   // 32-aligned groups
        if (t == 0) {
#pragma unroll
            for (int r = 0; r < 5; ++r) cntL[j * 6 + r] = (float)cnt[r];
            cntL[j * 6 + 5] = (float)(1023 - cnt[0] - cnt[1] - cnt[2] - cnt[3] - cnt[4]);
        }
    }

    // ---- phase 2: masked GEMM, 16 chunks of 64 i, BARRIER-FREE streaming ----
    f32x4 acc[5];
#pragma unroll
    for (int r = 0; r < 5; ++r) acc[r] = (f32x4){0.f, 0.f, 0.f, 0.f};

    const int E = (w << 4) + m;          // e-row owned by this lane
    const int bseg0 = q ^ (m & 7);       // ks=0 seg; ks=1 seg = (4+q)^(m&7)
    const int bseg1 = (4 + q) ^ (m & 7);
    const int csw = m << 1;

    for (int c = 0; c < 16; ++c) {
        if (c < 15) {
            issue_chunk(c + 1, (c + 1) & 1);              // prefetch next chunk
            asm volatile("s_waitcnt vmcnt(2)" ::: "memory");  // chunk c landed
        } else {
            asm volatile("s_waitcnt vmcnt(0)" ::: "memory");
        }
        const char* bb = smem + (c & 1) * 16384 + (w << 11) + (m << 7);
#pragma unroll
        for (int ks = 0; ks < 2; ++ks) {
            U4B bfr;
            bfr.u = *(const uint4*)(bb + ((ks ? bseg1 : bseg0) << 4));
            // full-index XOR swizzle (csw bits can cross the 16-word chunk)
            uint2 cw = *(const uint2*)&rel32[m * 256 +
                           (((c << 4) + (ks << 3) + (q << 1)) ^ csw)];
            // byte -> halfword expansion (shared across r)
            uint32_t hx01 = __builtin_amdgcn_perm(cw.x, cw.x, 0x01010000u) & 0x00FF00FFu;
            uint32_t hx23 = __builtin_amdgcn_perm(cw.x, cw.x, 0x03030202u) & 0x00FF00FFu;
            uint32_t hy01 = __builtin_amdgcn_perm(cw.y, cw.y, 0x01010000u) & 0x00FF00FFu;
            uint32_t hy23 = __builtin_amdgcn_perm(cw.y, cw.y, 0x03030202u) & 0x00FF00FFu;
#pragma unroll
            for (int r = 0; r < 5; ++r) {
                const uint32_t rm = 0x00010001u << r;
                U4B a;
#ifdef OH_MUL24
                const uint32_t mc = 0x3F80u >> r;   // 2^r * mc == 0x3F80 (bf16 1.0)
                a.u.x = (uint32_t)__builtin_amdgcn_mul_u24((int)(hx01 & rm), (int)mc);
                a.u.y = (uint32_t)__builtin_amdgcn_mul_u24((int)(hx23 & rm), (int)mc);
                a.u.z = (uint32_t)__builtin_amdgcn_mul_u24((int)(hy01 & rm), (int)mc);
                a.u.w = (uint32_t)__builtin_amdgcn_mul_u24((int)(hy23 & rm), (int)mc);
#else
                uint32_t g2;
                g2 = hx01 & rm; a.u.x = (g2 << (14 - r)) - (g2 << (7 - r));
                g2 = hx23 & rm; a.u.y = (g2 << (14 - r)) - (g2 << (7 - r));
                g2 = hy01 & rm; a.u.z = (g2 << (14 - r)) - (g2 << (7 - r));
                g2 = hy23 & rm; a.u.w = (g2 << (14 - r)) - (g2 << (7 - r));
#endif
                acc[r] = __builtin_amdgcn_mfma_f32_16x16x32_bf16(a.b, bfr.b, acc[r], 0, 0, 0);
            }
        }
        // no barrier: wave only touches its own buffer regions.
    }
    BARRIER_LGKM();   // all waves done with B buffers before SA overwrites

    // ---- S -> LDS (bf16) + S5 complement: S5 = T_b - sym[j] - sum_{r<5} S_r
#pragma unroll
    for (int r = 0; r < 5; ++r)
#pragma unroll
        for (int reg = 0; reg < 4; ++reg)
            SA[(q * 4 + reg) * SP + r * 128 + E] = f2bf(acc[r][reg]);
    {
        float ts = T4[((b << 2) + 0) * 128 + E] + T4[((b << 2) + 1) * 128 + E]
                 + T4[((b << 2) + 2) * 128 + E] + T4[((b << 2) + 3) * 128 + E];
#pragma unroll
        for (int reg = 0; reg < 4; ++reg) {
            float symj = X[((size_t)((b << 10) + j0 + (q << 2) + reg) << 7) + E];
            float s5 = ts - symj
                     - acc[0][reg] - acc[1][reg] - acc[2][reg] - acc[3][reg] - acc[4][reg];
            SA[(q * 4 + reg) * SP + 5 * 128 + E] = f2bf(s5);
        }
    }
    BARRIER_LGKM();

    // ---- phase 3: wave w owns e-slice [w*16, w*16+16); full K=768 ----
    {
        f32x4 c3 = (f32x4){0.f, 0.f, 0.f, 0.f};
#pragma unroll
        for (int kb = 0; kb < 24; ++kb) {
            U4B af, bw;
            af.u = *(const uint4*)&SA[m * SP + kb * 32 + q * 8];
            bw.u = *(const uint4*)&WtB[((size_t)(kb * 128 + (w << 4) + m)) * 32 + q * 8];
            c3 = __builtin_amdgcn_mfma_f32_16x16x32_bf16(af.b, bw.b, c3, 0, 0, 0);
        }

        // ---- epilogue: + sym + cnt_r*bias, direct store (no partials) ----
        const int e = (w << 4) + m;
        float be[6];
#pragma unroll
        for (int r = 0; r < 6; ++r) be[r] = bias[r * 128 + e];
#pragma unroll
        for (int reg = 0; reg < 4; ++reg) {
            const int j = q * 4 + reg;
            float add = c3[reg];
#pragma unroll
            for (int r = 0; r < 6; ++r) add += cntL[j * 6 + r] * be[r];
            size_t o = ((size_t)((b << 10) + j0 + j) << 7) + e;
            out[o] = X[o] + add;
        }
    }
}

extern "C" void kernel_launch(void* const* d_in, const int* in_sizes, int n_in,
                              void* d_out, int out_size, void* d_ws, size_t ws_size,
                              hipStream_t stream) {
    const float* symbols   = (const float*)d_in[0];  // [8,1024,128]
    const float* positions = (const float*)d_in[1];  // [8,1024,2]
    const float* W         = (const float*)d_in[2];  // [6,128,128]
    const float* bias      = (const float*)d_in[3];  // [6,128]
    float* out             = (float*)d_out;          // [8,1024,128]

    char* ws = (char*)d_ws;
    uint16_t* symT = (uint16_t*)ws;                  // 8*128*1024 bf16 = 2,097,152 B
    uint16_t* WtB  = (uint16_t*)(ws + 2097152);      // 24*128*32 bf16 =   196,608 B
    float*    T4   = (float*)(ws + 2097152 + 196608);// 8*4*128 f32    =    16,384 B

    prep_kernel<<<384, 256, 0, stream>>>(symbols, W, symT, WtB, T4);
    fused_kernel<<<512, 512, 0, stream>>>(symbols, positions, symT, WtB, bias, T4, out);
}